// Round 6
// baseline (205.591 us; speedup 1.0000x reference)
//
#include <hip/hip_runtime.h>
#include <hip/hip_bf16.h>

typedef float v2f __attribute__((ext_vector_type(2)));

// ---------------- problem constants ----------------
#define B_    4
#define C_    4
#define Q_    8
#define J_    5
#define T_    15
#define NSIG  65536
#define N2SIG 32768
#define NOUT  16384
#define NCH   (B_ * C_)

// ---------------- wavelet filters (constexpr -> inline literals) ----------
constexpr float H0Oc[13] = {
    -0.00455690456024f, -0.00543947593727f,  0.01702522388155f,  0.02382538479492f,
    -0.10671180468666f,  0.01186609203379f,  0.56881042071212f,  0.75614564389252f,
     0.27529538466888f, -0.11720388769911f, -0.03887280126882f,  0.03466034684485f,
    -0.00388321199915f };
constexpr float H1Oc[13] = {
    -0.00388321199915f, -0.03466034684485f, -0.03887280126882f,  0.11720388769911f,
     0.27529538466888f, -0.75614564389252f,  0.56881042071212f, -0.01186609203379f,
    -0.10671180468666f, -0.02382538479492f,  0.01702522388155f,  0.00543947593727f,
    -0.00455690456024f };
constexpr float H0Ac[10] = {
     0.03516384f, 0.0f, -0.08832942f, 0.23389032f, 0.76027237f,
     0.58751830f, 0.0f, -0.11430184f, 0.0f, 0.0f };
constexpr float H0Bc[10] = {
     0.0f, 0.0f, -0.11430184f, 0.0f, 0.58751830f,
     0.76027237f, 0.23389032f, -0.08832942f, 0.0f, 0.03516384f };
constexpr float H1Ac[10] = {
     0.0f, 0.0f, -0.11430184f, 0.0f, 0.58751830f,
    -0.76027237f, 0.23389032f, 0.08832942f, 0.0f, -0.03516384f };
constexpr float H1Bc[10] = {
    -0.03516384f, 0.0f, 0.08832942f, 0.23389032f, -0.76027237f,
     0.58751830f, 0.0f, -0.11430184f, 0.0f, 0.0f };

// fused two-stage lowpass+decimate: out[m] = sum_n g[n] * u[4m + n - 18]
struct Gtab { float v[37]; };
constexpr Gtab make_g() {
    Gtab g{};
    for (int n = 0; n < 37; ++n) {
        float s = 0.f;
        for (int k = 0; k < 13; ++k) {
            int l = n - 2 * k;
            if (l >= 0 && l < 13) s += H0Oc[k] * H0Oc[l];
        }
        g.v[n] = s;
    }
    return g;
}
constexpr Gtab cG = make_g();

// ---------------- tiling ----------------
#define M2    256                // final outputs per tile
#define NUcnt 1057               // 4*(M2-1) + 37
#define NUP   1064               // padded U plane stride (v2f elems)
#define NBcnt 1169               // bp pairs needed
#define NBP   1200               // sRI alloc (padded for grouped over-reads)
#define S_    1320               // x window (halo 73 left / 74 right)

// LDS carve (floats): X [0,1320) | L1 [1320,2640) | PP0=v2f@0 | PP1=v2f@2640 |
// U0=v2f@0 (1064) | U1=v2f@2128 (1064) | sRI=v2f@5280 (1200)
#define SMEM_FLOATS (5280 + 2 * NBP)   // 7680 floats = 30720 B

__device__ __forceinline__ v2f zmask(v2f a, bool ok) {
    if (!ok) { a.x = 0.f; a.y = 0.f; }
    return a;
}

// ---- 10-tap v2f conv, dilation DD, 2-sample grouped (11 taps / 2 outputs) ----
template<int DD>
__device__ __forceinline__ void conv10_pair(
        const v2f* __restrict__ src, v2f* __restrict__ dst, int dstShift,
        const float (&hA)[10], const float (&hB)[10],
        int pad, int plo, int count, int ofs, int tid) {
    const int npair = DD * ((count + 2 * DD - 1) / (2 * DD));
    for (int gi = tid; gi < npair; gi += 256) {
        const int base = plo + (gi / DD) * (2 * DD) + (gi % DD);
        v2f tap[11];
        #pragma unroll
        for (int k = 0; k < 11; k++) tap[k] = src[base + k * DD - pad];
        v2f o0; o0.x = 0.f; o0.y = 0.f;
        v2f o1; o1.x = 0.f; o1.y = 0.f;
        #pragma unroll
        for (int k = 0; k < 10; k++) {
            v2f hk; hk.x = hA[k]; hk.y = hB[k];
            o0 += hk * tap[k];
            o1 += hk * tap[k + 1];
        }
        const int p0 = base, p1 = base + DD;
        if (p0 < plo + count) dst[p0 - dstShift] = zmask(o0, (unsigned)(ofs + p0) < (unsigned)NSIG);
        if (p1 < plo + count) dst[p1 - dstShift] = zmask(o1, (unsigned)(ofs + p1) < (unsigned)NSIG);
    }
}

// ---- 10-tap scalar-source conv (d=1), 2-sample grouped, v2f dest ----
__device__ __forceinline__ void conv10_scalar_pair(
        const float* __restrict__ src, v2f* __restrict__ dst, int dstShift,
        const float (&hA)[10], const float (&hB)[10],
        int plo, int count, int ofs, int tid) {
    const int npair = (count + 1) / 2;
    for (int gi = tid; gi < npair; gi += 256) {
        const int base = plo + 2 * gi;
        float tap[11];
        #pragma unroll
        for (int k = 0; k < 11; k++) tap[k] = src[base + k - 4];
        v2f o0; o0.x = 0.f; o0.y = 0.f;
        v2f o1; o1.x = 0.f; o1.y = 0.f;
        #pragma unroll
        for (int k = 0; k < 10; k++) {
            v2f hk; hk.x = hA[k]; hk.y = hB[k];
            o0 += hk * tap[k];
            o1 += hk * tap[k + 1];
        }
        const int p0 = base, p1 = base + 1;
        if (p0 < plo + count) dst[p0 - dstShift] = zmask(o0, (unsigned)(ofs + p0) < (unsigned)NSIG);
        if (p1 < plo + count) dst[p1 - dstShift] = zmask(o1, (unsigned)(ofs + p1) < (unsigned)NSIG);
    }
}

// ---------------- post stage (u + fused downsample), templated on D ------
template<int D>
__device__ __forceinline__ void post_stage(
        const v2f* __restrict__ sRI, v2f* __restrict__ U0, v2f* __restrict__ U1,
        const float* __restrict__ cw, const float* __restrict__ roots,
        float beta, int j, int b, int c, int m0, int mt, int tid,
        float* __restrict__ out) {
    const float lg_is = -0.5f * (float)j;                // log2(inv_scale)
    const float beta2 = beta * exp2f(0.5f * (float)j);   // beta * scale
    const int   u_lo  = 4 * m0 - 18;
    constexpr int NG  = D * ((NUcnt + 4 * D - 1) / (4 * D));

    for (int g2 = 0; g2 < 2; ++g2) {
        // uniform weights / alphas for this group of 4 q's
        float w[4][T_], al[4], cq[4];
        #pragma unroll
        for (int qq = 0; qq < 4; ++qq) {
            const int o = c * Q_ + g2 * 4 + qq;
            #pragma unroll
            for (int t = 0; t < T_; t++) w[qq][t] = cw[(size_t)(j * 32 + o) * T_ + t];
            al[qq] = 1.f / (1.f + __expf(-roots[j * 32 + o]));
            cq[qq] = al[qq] * lg_is;
        }

        // ---- u stage: 4 samples (spaced D) per thread share 18 taps ----
        for (int gi = tid; gi < NG; gi += 256) {
            const int base = (gi / D) * (4 * D) + (gi % D);
            const v2f* tp = sRI + (base + 56 - 7 * D);
            v2f tap[18];
            #pragma unroll
            for (int t = 0; t < 18; t++) tap[t] = tp[t * D];
            #pragma unroll
            for (int r = 0; r < 4; r++) {
                const int i = base + r * D;
                if (i < NUcnt) {
                    const int n = u_lo + i;
                    const bool ok = ((unsigned)n < (unsigned)NSIG);
                    float uq[4];
                    #pragma unroll
                    for (int qq = 0; qq < 4; ++qq) {
                        v2f ri; ri.x = 0.f; ri.y = 0.f;
                        #pragma unroll
                        for (int t = 0; t < T_; t++) ri += w[qq][t] * tap[r + t];
                        float z2 = fmaf(ri.x, ri.x, ri.y * ri.y);
                        float us = sqrtf(z2);
                        float lg = __log2f(us + beta2);
                        float u  = exp2f(fmaf(al[qq], lg, cq[qq]));
                        uq[qq] = ok ? u : 0.f;
                    }
                    v2f p0; p0.x = uq[0]; p0.y = uq[1];
                    v2f p1; p1.x = uq[2]; p1.y = uq[3];
                    U0[i] = p0; U1[i] = p1;
                }
            }
        }
        __syncthreads();

        // ---- fused 37-tap stride-4 downsample, q-pair packed ----
        {
            const int m = m0 + tid;
            const bool edge = (mt == 0 && tid < 3) || (mt == 63 && tid >= 253);
            #pragma unroll
            for (int qp = 0; qp < 2; ++qp) {
                const v2f* up = qp ? U1 : U0;
                v2f acc; acc.x = 0.f; acc.y = 0.f;
                #pragma unroll
                for (int n = 0; n < 37; ++n) acc += cG.v[n] * up[4 * tid + n];
                if (edge) {
                    v2f a2; a2.x = 0.f; a2.y = 0.f;
                    for (int k = 0; k < 13; ++k) {
                        int p = 2 * m + k - 6;
                        if (p < 0 || p >= N2SIG) continue;
                        v2f v; v.x = 0.f; v.y = 0.f;
                        for (int l = 0; l < 13; ++l)
                            v += H0Oc[l] * up[4 * tid + 2 * k + l];
                        a2 += H0Oc[k] * v;
                    }
                    acc = a2;
                }
                const int o = c * Q_ + g2 * 4 + 2 * qp;
                out[((size_t)b * 160 + j * 32 + o)     * NOUT + m] = acc.x;
                out[((size_t)b * 160 + j * 32 + o + 1) * NOUT + m] = acc.y;
            }
        }
        __syncthreads();
    }
}

// ---------------- fused kernel ----------------
__global__ __launch_bounds__(256, 4) void murenn_all(
        const float* __restrict__ x,
        const float* __restrict__ cw,
        const float* __restrict__ roots,
        const float* __restrict__ beta_p,
        float* __restrict__ out) {
    __shared__ __align__(16) float smem[SMEM_FLOATS];
    float* X   = smem;
    float* L1  = smem + S_;
    v2f*   PP0 = (v2f*)smem;
    v2f*   PP1 = (v2f*)(smem + 2 * S_);
    v2f*   U0  = (v2f*)smem;
    v2f*   U1  = (v2f*)(smem + 2 * NUP);
    v2f*   sRI = (v2f*)(smem + 4 * S_);

    const int tid = threadIdx.x;
    const int mt  = blockIdx.x;              // 0..63
    const int ch  = blockIdx.y;              // b*C + c
    const int j   = blockIdx.z;              // 0..4
    const int b   = ch >> 2, c = ch & 3;
    const int m0  = mt * M2;
    const int ofs = 4 * m0 - 147;            // window start (bp index 0 at p=73)
    const float beta = beta_p[0];
    const float* xc = x + (size_t)ch * NSIG;

    // ---- load x window ----
    for (int p = tid; p < S_; p += 256) {
        int g = ofs + p;
        X[p] = ((unsigned)g < (unsigned)NSIG) ? xc[g] : 0.f;
    }
    __syncthreads();

    // ---- UDTCWT chain (branches block-uniform in j) ----
    if (j == 0) {
        // bp0 = 13-tap H1O on x, trees identical; 2-sample grouped
        for (int gi = tid; gi < (NBcnt + 1) / 2; gi += 256) {
            const int p = 73 + 2 * gi;
            float tap[14];
            #pragma unroll
            for (int k = 0; k < 14; k++) tap[k] = X[p + k - 6];
            float a0 = 0.f, a1 = 0.f;
            #pragma unroll
            for (int k = 0; k < 13; k++) {
                a0 = fmaf(H1Oc[k], tap[k],     a0);
                a1 = fmaf(H1Oc[k], tap[k + 1], a1);
            }
            if ((unsigned)(ofs + p) >= (unsigned)NSIG) a0 = 0.f;
            if ((unsigned)(ofs + p + 1) >= (unsigned)NSIG) a1 = 0.f;
            v2f r0; r0.x = a0; r0.y = a0;
            v2f r1; r1.x = a1; r1.y = a1;
            sRI[p - 73] = r0;
            if (p + 1 < 73 + NBcnt) sRI[p + 1 - 73] = r1;
        }
    } else {
        // lv0: la1 = conv13(x, H0O) -> L1, 2-sample grouped (range [6,1313))
        for (int gi = tid; gi < 654; gi += 256) {
            const int p = 6 + 2 * gi;
            float tap[14];
            #pragma unroll
            for (int k = 0; k < 14; k++) tap[k] = X[p + k - 6];
            float a0 = 0.f, a1 = 0.f;
            #pragma unroll
            for (int k = 0; k < 13; k++) {
                a0 = fmaf(H0Oc[k], tap[k],     a0);
                a1 = fmaf(H0Oc[k], tap[k + 1], a1);
            }
            L1[p] = ((unsigned)(ofs + p) < (unsigned)NSIG) ? a0 : 0.f;
            if (p + 1 < 1313)
                L1[p + 1] = ((unsigned)(ofs + p + 1) < (unsigned)NSIG) ? a1 : 0.f;
        }
        __syncthreads();
        if (j == 1) {
            conv10_scalar_pair(L1, sRI, 73, H1Ac, H1Bc, 73, NBcnt, ofs, tid);
        } else {
            // lv1 (d=1, pad 4): (la2,lb2) -> PP1 over [10,1308)
            conv10_scalar_pair(L1, PP1, 0, H0Ac, H0Bc, 10, 1298, ofs, tid);
            __syncthreads();
            if (j == 2) {
                conv10_pair<2>(PP1, sRI, 73, H1Ac, H1Bc, 9, 73, NBcnt, ofs, tid);
            } else {
                // lv2 (d=2, pad 9): (la3,lb3) -> PP0 over [19,1299)
                conv10_pair<2>(PP1, PP0, 0, H0Ac, H0Bc, 9, 19, 1280, ofs, tid);
                __syncthreads();
                if (j == 3) {
                    conv10_pair<4>(PP0, sRI, 73, H1Ac, H1Bc, 18, 73, NBcnt, ofs, tid);
                } else {
                    // lv3 (d=4, pad 18): (la4,lb4) -> PP1 over [37,1281)
                    conv10_pair<4>(PP0, PP1, 0, H0Ac, H0Bc, 18, 37, 1244, ofs, tid);
                    __syncthreads();
                    // j == 4 bandpass (d=8, pad 36)
                    conv10_pair<8>(PP1, sRI, 73, H1Ac, H1Bc, 36, 73, NBcnt, ofs, tid);
                }
            }
        }
    }
    __syncthreads();
    // PP/X/L1 dead: region becomes U planes.

    if (j == 0)      post_stage<1>(sRI, U0, U1, cw, roots, beta, 0, b, c, m0, mt, tid, out);
    else if (j == 1) post_stage<1>(sRI, U0, U1, cw, roots, beta, 1, b, c, m0, mt, tid, out);
    else if (j == 2) post_stage<2>(sRI, U0, U1, cw, roots, beta, 2, b, c, m0, mt, tid, out);
    else if (j == 3) post_stage<4>(sRI, U0, U1, cw, roots, beta, 3, b, c, m0, mt, tid, out);
    else             post_stage<8>(sRI, U0, U1, cw, roots, beta, 4, b, c, m0, mt, tid, out);
}

// ---------------- launch ----------------
extern "C" void kernel_launch(void* const* d_in, const int* in_sizes, int n_in,
                              void* d_out, int out_size, void* d_ws, size_t ws_size,
                              hipStream_t stream) {
    (void)in_sizes; (void)n_in; (void)out_size; (void)d_ws; (void)ws_size;
    const float* x     = (const float*)d_in[0];
    const float* cw    = (const float*)d_in[1];
    const float* roots = (const float*)d_in[2];
    const float* beta  = (const float*)d_in[3];
    float* out = (float*)d_out;

    dim3 grid(NOUT / M2, NCH, J_);       // (64, 16, 5)
    murenn_all<<<grid, 256, 0, stream>>>(x, cw, roots, beta, out);
}